// Round 1
// baseline (331.906 us; speedup 1.0000x reference)
//
#include <hip/hip_runtime.h>

#define NB 128  // batch size (lanes per node row); B = in_sizes[0]/N = 128

// ---------------- setup kernels ----------------

__global__ void zero_kernel(int* __restrict__ p, int n) {
  int i = blockIdx.x * blockDim.x + threadIdx.x;
  if (i < n) p[i] = 0;
}

__global__ void hist_kernel(const int* __restrict__ src, const int* __restrict__ tgt,
                            int* __restrict__ cntS, int* __restrict__ cntT, int E) {
  int e = blockIdx.x * blockDim.x + threadIdx.x;
  if (e < E) {
    atomicAdd(&cntS[src[e]], 1);
    atomicAdd(&cntT[tgt[e]], 1);
  }
}

// one block per array (blockIdx.x 0 -> S, 1 -> T); 256 threads x 8 items = 2048 >= N+1
__global__ void scan_kernel(const int* __restrict__ cntS, const int* __restrict__ cntT,
                            int* __restrict__ offS, int* __restrict__ offT,
                            int* __restrict__ curS, int* __restrict__ curT, int N) {
  const int* cnt = (blockIdx.x == 0) ? cntS : cntT;
  int* off = (blockIdx.x == 0) ? offS : offT;
  int* cur = (blockIdx.x == 0) ? curS : curT;
  __shared__ int tsum[256];
  int tid = threadIdx.x;
  int base = tid * 8;
  int v[8];
  int s = 0;
#pragma unroll
  for (int i = 0; i < 8; ++i) {
    int idx = base + i;
    int c = (idx < N) ? cnt[idx] : 0;
    v[i] = s;  // exclusive within-thread prefix
    s += c;
  }
  tsum[tid] = s;
  __syncthreads();
  for (int d = 1; d < 256; d <<= 1) {
    int t = (tid >= d) ? tsum[tid - d] : 0;
    __syncthreads();
    tsum[tid] += t;
    __syncthreads();
  }
  int tbase = tsum[tid] - s;  // exclusive block prefix
#pragma unroll
  for (int i = 0; i < 8; ++i) {
    int idx = base + i;
    if (idx < N) {
      int o = tbase + v[i];
      off[idx] = o;
      cur[idx] = o;
    } else if (idx == N) {
      off[idx] = tbase + v[i];  // total = E
    }
  }
}

__global__ void scatter_kernel(const int* __restrict__ src, const int* __restrict__ tgt,
                               const float* __restrict__ w,
                               int* __restrict__ curS, int* __restrict__ curT,
                               int2* __restrict__ edgeS, int2* __restrict__ edgeT, int E) {
  int e = blockIdx.x * blockDim.x + threadIdx.x;
  if (e < E) {
    int s = src[e], t = tgt[e];
    int wb = __float_as_int(w[e]);
    int p = atomicAdd(&curS[s], 1);
    edgeS[p] = make_int2(t, wb);  // mu pass: grouped by src, needs (tgt, w)
    int q = atomicAdd(&curT[t], 1);
    edgeT[q] = make_int2(s, wb);  // agg pass: grouped by tgt, needs (src, w)
  }
}

// x[b*N+n] -> xt[n*NB+b]; also fxt = tanh(x)
__global__ void transpose_in_kernel(const float* __restrict__ x, float* __restrict__ xt,
                                    float* __restrict__ fxt, int N) {
  int gid = blockIdx.x * blockDim.x + threadIdx.x;  // = n*NB + b
  if (gid >= N * NB) return;
  int n = gid >> 7;
  int b = gid & (NB - 1);
  float v = x[b * N + n];
  xt[gid] = v;
  fxt[gid] = tanhf(v);
}

__global__ void transpose_out_kernel(const float* __restrict__ xt, float* __restrict__ out, int N) {
  int gid = blockIdx.x * blockDim.x + threadIdx.x;  // = b*N + n (coalesced write)
  if (gid >= N * NB) return;
  int b = gid / N;
  int n = gid - b * N;
  out[gid] = xt[n * NB + b];
}

// ---------------- main loop kernels ----------------
// phase1: mu[n] = sum_{e: src==n} w*fxt[tgt]; err[n] = (x[n]-mu)*mask[n]
__global__ __launch_bounds__(NB) void phase1_kernel(
    const float* __restrict__ xt, const float* __restrict__ fxt,
    float* __restrict__ err, const int* __restrict__ offS,
    const int2* __restrict__ edgeS, const float* __restrict__ mask) {
  const int n = blockIdx.x;
  const int b = threadIdx.x;
  const int p0 = offS[n], p1 = offS[n + 1];
  float mu0 = 0.f, mu1 = 0.f;
  int p = p0;
  for (; p + 1 < p1; p += 2) {
    int2 e0 = edgeS[p];
    int2 e1 = edgeS[p + 1];
    mu0 += __int_as_float(e0.y) * fxt[e0.x * NB + b];
    mu1 += __int_as_float(e1.y) * fxt[e1.x * NB + b];
  }
  if (p < p1) {
    int2 e0 = edgeS[p];
    mu0 += __int_as_float(e0.y) * fxt[e0.x * NB + b];
  }
  const int i = n * NB + b;
  err[i] = (xt[i] - (mu0 + mu1)) * mask[n];
}

// phase2: agg[n] = sum_{e: tgt==n} w*err[src]; dx = err - (1-fx^2)*agg;
//         x -= 0.5*dx*mask; fx = tanh(x)
__global__ __launch_bounds__(NB) void phase2_kernel(
    float* __restrict__ xt, float* __restrict__ fxt,
    const float* __restrict__ err, const int* __restrict__ offT,
    const int2* __restrict__ edgeT, const float* __restrict__ mask) {
  const int n = blockIdx.x;
  const int b = threadIdx.x;
  const int p0 = offT[n], p1 = offT[n + 1];
  float a0 = 0.f, a1 = 0.f;
  int p = p0;
  for (; p + 1 < p1; p += 2) {
    int2 e0 = edgeT[p];
    int2 e1 = edgeT[p + 1];
    a0 += __int_as_float(e0.y) * err[e0.x * NB + b];
    a1 += __int_as_float(e1.y) * err[e1.x * NB + b];
  }
  if (p < p1) {
    int2 e0 = edgeT[p];
    a0 += __int_as_float(e0.y) * err[e0.x * NB + b];
  }
  const int i = n * NB + b;
  const float agg = a0 + a1;
  const float xc = xt[i];
  const float e = err[i];
  const float fx = fxt[i];  // = tanh(xc), cached from previous update
  const float dx = e - (1.f - fx * fx) * agg;
  const float xn = xc - 0.5f * dx * mask[n];
  xt[i] = xn;
  fxt[i] = tanhf(xn);
}

// ---------------- host ----------------

extern "C" void kernel_launch(void* const* d_in, const int* in_sizes, int n_in,
                              void* d_out, int out_size, void* d_ws, size_t ws_size,
                              hipStream_t stream) {
  const float* x = (const float*)d_in[0];
  const int* ei = (const int*)d_in[1];
  const float* w = (const float*)d_in[2];
  const float* mask = (const float*)d_in[3];
  const int E = in_sizes[2];      // 131072
  const int N = in_sizes[3];      // 2000
  const int NBtot = in_sizes[0];  // N*B = 256000
  const int* src = ei;
  const int* tgt = ei + E;
  float* out = (float*)d_out;

  size_t off = 0;
  auto alloc = [&](size_t bytes) -> void* {
    off = (off + 255) & ~(size_t)255;
    void* p = (char*)d_ws + off;
    off += bytes;
    return p;
  };
  float* xt = (float*)alloc((size_t)NBtot * 4);
  float* fxt = (float*)alloc((size_t)NBtot * 4);
  float* err = (float*)alloc((size_t)NBtot * 4);
  int* cntS = (int*)alloc(2048 * 4);
  int* cntT = (int*)alloc(2048 * 4);
  int* offS = (int*)alloc(2048 * 4);
  int* offT = (int*)alloc(2048 * 4);
  int* curS = (int*)alloc(2048 * 4);
  int* curT = (int*)alloc(2048 * 4);
  int2* edgeS = (int2*)alloc((size_t)E * 8);
  int2* edgeT = (int2*)alloc((size_t)E * 8);

  // zero both count arrays (contiguous: cntS then cntT)
  zero_kernel<<<(4096 + 255) / 256, 256, 0, stream>>>(cntS, 4096);
  hist_kernel<<<(E + 255) / 256, 256, 0, stream>>>(src, tgt, cntS, cntT, E);
  scan_kernel<<<2, 256, 0, stream>>>(cntS, cntT, offS, offT, curS, curT, N);
  scatter_kernel<<<(E + 255) / 256, 256, 0, stream>>>(src, tgt, w, curS, curT, edgeS, edgeT, E);
  transpose_in_kernel<<<(NBtot + 255) / 256, 256, 0, stream>>>(x, xt, fxt, N);

  for (int it = 0; it < 10; ++it) {
    phase1_kernel<<<N, NB, 0, stream>>>(xt, fxt, err, offS, edgeS, mask);
    phase2_kernel<<<N, NB, 0, stream>>>(xt, fxt, err, offT, edgeT, mask);
  }

  transpose_out_kernel<<<(NBtot + 255) / 256, 256, 0, stream>>>(xt, out, N);
}